// Round 1
// baseline (871.030 us; speedup 1.0000x reference)
//
#include <hip/hip_runtime.h>
#include <math.h>

#define CC 1024
#define SS 16
#define DD 512
#define RR (CC*SS)
#define EPSV 1e-8f

// ws layout (floats):
//   mean:    [CC*DD]          off 0
//   nmean:   [CC]             off CC*DD
//   nx:      [RR]             off CC*DD + CC
//   simpos:  [RR]             off CC*DD + CC + RR
//   partial: [256]            off CC*DD + CC + 2*RR
#define OFF_MEAN   0
#define OFF_NMEAN  (CC*DD)
#define OFF_NX     (CC*DD + CC)
#define OFF_SIMPOS (CC*DD + CC + RR)
#define OFF_PART   (CC*DD + CC + 2*RR)

// ---------------- Kernel 1: per-class precompute ----------------
// grid = C blocks, 256 threads. Computes mean_c, ||mean_c||, per-row ||x||
// and sim_pos (leave-one-out cosine) via dot(x, sum-x) identities.
__global__ __launch_bounds__(256) void k_precompute(
    const float* __restrict__ x, float* __restrict__ mean,
    float* __restrict__ nmean, float* __restrict__ nx,
    float* __restrict__ simpos) {
  __shared__ float xs[SS * DD];   // 32 KB
  __shared__ float sums[DD];      // 2 KB
  __shared__ float red[4];
  const int j = blockIdx.x;
  const int tid = threadIdx.x;
  const float* xj = x + (size_t)j * SS * DD;
  for (int idx = tid; idx < SS * DD; idx += 256) xs[idx] = xj[idx];
  __syncthreads();
  float m2 = 0.f;
  for (int d = tid; d < DD; d += 256) {
    float s = 0.f;
#pragma unroll
    for (int i = 0; i < SS; ++i) s += xs[i * DD + d];
    sums[d] = s;
    float m = s * (1.0f / SS);
    mean[(size_t)j * DD + d] = m;
    m2 += m * m;
  }
#pragma unroll
  for (int off = 32; off > 0; off >>= 1) m2 += __shfl_xor(m2, off, 64);
  const int wid = tid >> 6, lane = tid & 63;
  if (lane == 0) red[wid] = m2;
  __syncthreads();
  if (tid == 0) nmean[j] = sqrtf(red[0] + red[1] + red[2] + red[3]);
  // per-row quantities: one wave per row, 4 rows per wave
  for (int i = wid; i < SS; i += 4) {
    float nx2 = 0.f, dxs = 0.f, t2 = 0.f;
    for (int d = lane; d < DD; d += 64) {
      float xv = xs[i * DD + d];
      float sc = sums[d];
      nx2 = fmaf(xv, xv, nx2);
      dxs = fmaf(xv, sc, dxs);
      float tv = sc - xv;
      t2 = fmaf(tv, tv, t2);
    }
#pragma unroll
    for (int off = 32; off > 0; off >>= 1) {
      nx2 += __shfl_xor(nx2, off, 64);
      dxs += __shfl_xor(dxs, off, 64);
      t2  += __shfl_xor(t2,  off, 64);
    }
    if (lane == 0) {
      float nxv = sqrtf(nx2);
      float tn  = sqrtf(t2);
      float num = (dxs - nx2) * (1.0f / (SS - 1));
      float den = fmaxf(nxv * tn * (1.0f / (SS - 1)), EPSV);
      nx[j * SS + i] = nxv;
      simpos[j * SS + i] = num / den;
    }
  }
}

// ---------------- Kernel 2: fused sim_neg GEMM + streaming LSE ----------------
// grid = 256 blocks (64 rows each), 256 threads. Block tile 64 rows x 64 cols,
// thread tile 4x4, d-tiled by 64 with +1 LDS padding.
#define BT 64
#define DT 64
#define LDP 65

__global__ __launch_bounds__(256) void k_main(
    const float* __restrict__ x, const float* __restrict__ mean,
    const float* __restrict__ nmean, const float* __restrict__ nx,
    const float* __restrict__ simpos, const float* __restrict__ wptr,
    const float* __restrict__ bptr, float* __restrict__ partial) {
  __shared__ float xs[BT * LDP];   // 16.6 KB
  __shared__ float ms[BT * LDP];   // 16.6 KB
  __shared__ float rmax[BT], rsum[BT], dlog[BT], lred[BT];
  const int tid = threadIdx.x;
  const int r0 = blockIdx.x * BT;
  const float wv = wptr[0], bv = bptr[0];
  const float wp = log1pf(expf(wv));   // softplus
  const int tx = tid & 15, ty = tid >> 4;
  if (tid < BT) { rmax[tid] = -INFINITY; rsum[tid] = 0.f; dlog[tid] = 0.f; }
  float nxr[4];
#pragma unroll
  for (int i = 0; i < 4; ++i) nxr[i] = nx[r0 + ty * 4 + i];
  __syncthreads();

  for (int ct = 0; ct < CC / BT; ++ct) {
    float acc[4][4] = {};
    for (int dt = 0; dt < DD / DT; ++dt) {
      __syncthreads();
      for (int idx = tid; idx < BT * DT; idx += 256) {
        int rr = idx >> 6, dd = idx & 63;
        xs[rr * LDP + dd] = x[(size_t)(r0 + rr) * DD + dt * DT + dd];
        ms[rr * LDP + dd] = mean[(size_t)(ct * BT + rr) * DD + dt * DT + dd];
      }
      __syncthreads();
#pragma unroll 4
      for (int dd = 0; dd < DT; ++dd) {
        float a[4], bb[4];
#pragma unroll
        for (int i = 0; i < 4; ++i)  a[i]  = xs[(ty * 4 + i) * LDP + dd];
#pragma unroll
        for (int jj = 0; jj < 4; ++jj) bb[jj] = ms[(tx * 4 + jj) * LDP + dd];
#pragma unroll
        for (int i = 0; i < 4; ++i)
#pragma unroll
          for (int jj = 0; jj < 4; ++jj)
            acc[i][jj] = fmaf(a[i], bb[jj], acc[i][jj]);
      }
    }
    // logits for this 64-col tile
    float nmc[4];
#pragma unroll
    for (int jj = 0; jj < 4; ++jj) nmc[jj] = nmean[ct * BT + tx * 4 + jj];
#pragma unroll
    for (int i = 0; i < 4; ++i) {
      const int r = r0 + ty * 4 + i;
      const int jr = r >> 4;   // diagonal class index
      float lg[4];
#pragma unroll
      for (int jj = 0; jj < 4; ++jj) {
        const int c = ct * BT + tx * 4 + jj;
        float sim;
        if (c == jr) sim = simpos[r];
        else sim = acc[i][jj] / fmaxf(nxr[i] * nmc[jj], EPSV);
        lg[jj] = fmaf(wp, sim, bv);
        if (c == jr) dlog[ty * 4 + i] = lg[jj];
      }
      // tile max/sum across the 16 lanes covering this row
      float m = fmaxf(fmaxf(lg[0], lg[1]), fmaxf(lg[2], lg[3]));
#pragma unroll
      for (int off = 1; off < 16; off <<= 1) m = fmaxf(m, __shfl_xor(m, off, 64));
      float s = 0.f;
#pragma unroll
      for (int jj = 0; jj < 4; ++jj) s += expf(lg[jj] - m);
#pragma unroll
      for (int off = 1; off < 16; off <<= 1) s += __shfl_xor(s, off, 64);
      if (tx == 0) {
        const int row = ty * 4 + i;
        float om = rmax[row];
        float nm = fmaxf(om, m);
        rsum[row] = rsum[row] * expf(om - nm) + s * expf(m - nm);
        rmax[row] = nm;
      }
    }
  }
  __syncthreads();
  if (tid < BT) lred[tid] = rmax[tid] + logf(rsum[tid]) - dlog[tid];
  __syncthreads();
  if (tid == 0) {
    float t = 0.f;
    for (int i = 0; i < BT; ++i) t += lred[i];
    partial[blockIdx.x] = t;
  }
}

// ---------------- Kernel 3: final reduce ----------------
__global__ __launch_bounds__(256) void k_final(const float* __restrict__ partial,
                                               float* __restrict__ out) {
  __shared__ float red[4];
  const int tid = threadIdx.x;
  float v = partial[tid];
#pragma unroll
  for (int off = 32; off > 0; off >>= 1) v += __shfl_xor(v, off, 64);
  if ((tid & 63) == 0) red[tid >> 6] = v;
  __syncthreads();
  if (tid == 0) out[0] = (red[0] + red[1] + red[2] + red[3]) * (1.0f / RR);
}

extern "C" void kernel_launch(void* const* d_in, const int* in_sizes, int n_in,
                              void* d_out, int out_size, void* d_ws, size_t ws_size,
                              hipStream_t stream) {
  const float* x = (const float*)d_in[0];
  const float* w = (const float*)d_in[1];
  const float* b = (const float*)d_in[2];
  float* out = (float*)d_out;
  float* ws = (float*)d_ws;

  float* mean   = ws + OFF_MEAN;
  float* nmean  = ws + OFF_NMEAN;
  float* nx     = ws + OFF_NX;
  float* simpos = ws + OFF_SIMPOS;
  float* part   = ws + OFF_PART;

  k_precompute<<<CC, 256, 0, stream>>>(x, mean, nmean, nx, simpos);
  k_main<<<RR / BT, 256, 0, stream>>>(x, mean, nmean, nx, simpos, w, b, part);
  k_final<<<1, 256, 0, stream>>>(part, out);
}

// Round 2
// 165.450 us; speedup vs baseline: 5.2646x; 5.2646x over previous
//
#include <hip/hip_runtime.h>
#include <math.h>

#define CC 1024
#define SS 16
#define DD 512
#define RR (CC*SS)
#define EPSV 1e-8f

typedef __attribute__((ext_vector_type(8))) short short8;
typedef __attribute__((ext_vector_type(4))) float f32x4;

// ws layout (float units)
#define OFF_MN     0                      // bf16[CC*DD] normalized mean  (CC*DD/2 floats)
#define OFF_NX     (CC*DD/2)              // float[RR]
#define OFF_SIMPOS (OFF_NX + RR)          // float[RR]
#define OFF_PM     (OFF_SIMPOS + RR)      // float[RR*4] partial max
#define OFF_PS     (OFF_PM + RR*4)        // float[RR*4] partial sum
#define OFF_P2     (OFF_PS + RR*4)        // float[64]

__device__ __forceinline__ unsigned short f2bf(float f) {
  unsigned u = __float_as_uint(f);
  u += 0x7fffu + ((u >> 16) & 1u);       // round-to-nearest-even
  return (unsigned short)(u >> 16);
}

__device__ __forceinline__ void async16(void* l, const void* g) {
  __builtin_amdgcn_global_load_lds(
      (const __attribute__((address_space(1))) void*)g,
      (__attribute__((address_space(3))) void*)l, 16, 0, 0);
}

__device__ __forceinline__ float softplusf(float v) {
  return (v > 20.f) ? v : log1pf(expf(v));
}

// ---------------- Kernel 1: per-class precompute ----------------
// grid = CC blocks. Writes bf16 normalized mean rows, nx, simpos.
__global__ __launch_bounds__(256) void k_pre(
    const float* __restrict__ x, unsigned short* __restrict__ mn,
    float* __restrict__ nx, float* __restrict__ simpos) {
  __shared__ float xs[SS * DD];
  __shared__ float sums[DD];
  __shared__ float red[4];
  __shared__ float snm;
  const int j = blockIdx.x, tid = threadIdx.x;
  const float4* xj = (const float4*)(x + (size_t)j * SS * DD);
  float4* xs4 = (float4*)xs;
  for (int i = tid; i < SS * DD / 4; i += 256) xs4[i] = xj[i];
  __syncthreads();
  float m2 = 0.f;
  for (int d = tid; d < DD; d += 256) {
    float s = 0.f;
#pragma unroll
    for (int i = 0; i < SS; ++i) s += xs[i * DD + d];
    sums[d] = s;
    float m = s * (1.0f / SS);
    m2 += m * m;
  }
#pragma unroll
  for (int off = 32; off > 0; off >>= 1) m2 += __shfl_xor(m2, off, 64);
  const int wid = tid >> 6, lane = tid & 63;
  if (lane == 0) red[wid] = m2;
  __syncthreads();
  if (tid == 0) snm = sqrtf(red[0] + red[1] + red[2] + red[3]);
  __syncthreads();
  const float inm = (1.0f / SS) / snm;
  for (int d = tid; d < DD; d += 256)
    mn[(size_t)j * DD + d] = f2bf(sums[d] * inm);
  for (int i = wid; i < SS; i += 4) {
    float nx2 = 0.f, dxs = 0.f, t2 = 0.f;
    for (int d = lane; d < DD; d += 64) {
      float xv = xs[i * DD + d];
      float sc = sums[d];
      nx2 = fmaf(xv, xv, nx2);
      dxs = fmaf(xv, sc, dxs);
      float tv = sc - xv;
      t2 = fmaf(tv, tv, t2);
    }
#pragma unroll
    for (int off = 32; off > 0; off >>= 1) {
      nx2 += __shfl_xor(nx2, off, 64);
      dxs += __shfl_xor(dxs, off, 64);
      t2  += __shfl_xor(t2,  off, 64);
    }
    if (lane == 0) {
      float nxv = sqrtf(nx2);
      float tn  = sqrtf(t2);
      float num = (dxs - nx2) * (1.0f / (SS - 1));
      float den = fmaxf(nxv * tn * (1.0f / (SS - 1)), EPSV);
      nx[j * SS + i] = nxv;
      simpos[j * SS + i] = num / den;
    }
  }
}

// ---------------- Kernel 2: MFMA GEMM + fused streaming LSE ----------------
// grid = 256 row-blocks x 4 col-splits. Block: 4 waves x 16 rows = 64 rows,
// 256 cols per block in 4 chunks of 64. A in registers (bf16), B via
// global_load_lds into padded LDS (stride 520 shorts -> conflict-free b128).
#define LDB 520

__global__ __launch_bounds__(256) void k_gemm(
    const float* __restrict__ x, const unsigned short* __restrict__ mn,
    const float* __restrict__ nx, const float* __restrict__ simpos,
    const float* __restrict__ wptr, const float* __restrict__ bptr,
    float* __restrict__ pm, float* __restrict__ ps) {
  __shared__ unsigned short bs[64 * LDB];   // 66.6 KB
  const int tid = threadIdx.x;
  const int wid = tid >> 6, lane = tid & 63;
  const int cL = lane & 15, quad = lane >> 4;
  const int rb = blockIdx.x & 255, cb = blockIdx.x >> 8;
  const int r0 = rb * 64;
  const int cbase = cb * 256;
  const float wv = wptr[0], bv = bptr[0];
  const float wp = softplusf(wv);

  // A fragments: 16 rows x K=512, row = r0 + wid*16 + cL, in registers
  const int arow = r0 + wid * 16 + cL;
  const float* xr = x + (size_t)arow * DD;
  const float invn = 1.0f / nx[arow];
  short8 af[16];
#pragma unroll 4
  for (int kc = 0; kc < 16; ++kc) {
    const int k0 = kc * 32 + quad * 8;
    float4 p = *(const float4*)(xr + k0);
    float4 q = *(const float4*)(xr + k0 + 4);
    short8 v;
    v[0] = f2bf(p.x * invn); v[1] = f2bf(p.y * invn);
    v[2] = f2bf(p.z * invn); v[3] = f2bf(p.w * invn);
    v[4] = f2bf(q.x * invn); v[5] = f2bf(q.y * invn);
    v[6] = f2bf(q.z * invn); v[7] = f2bf(q.w * invn);
    af[kc] = v;
  }

  const int jw = r0 / 16 + wid;   // the single class covering this wave's rows
  float sp[4], rm[4], rs[4];
#pragma unroll
  for (int r = 0; r < 4; ++r) {
    sp[r] = simpos[r0 + wid * 16 + quad * 4 + r];
    rm[r] = -INFINITY;
    rs[r] = 0.f;
  }

  for (int cc = 0; cc < 4; ++cc) {
    const int c0 = cbase + cc * 64;
    // stage 64 mean rows (1 KB each) into padded LDS; wave handles rows wid+4t
    const unsigned short* gsrc = mn + (size_t)c0 * DD;
    for (int rr = wid; rr < 64; rr += 4)
      async16(&bs[rr * LDB + lane * 8], gsrc + rr * DD + lane * 8);
    __syncthreads();   // drains vmcnt(0) for global_load_lds

    f32x4 acc[4];
#pragma unroll
    for (int f = 0; f < 4; ++f) acc[f] = (f32x4){0.f, 0.f, 0.f, 0.f};
#pragma unroll 4
    for (int kc = 0; kc < 16; ++kc) {
#pragma unroll
      for (int f = 0; f < 4; ++f) {
        short8 bfr = *(const short8*)&bs[(f * 16 + cL) * LDB + kc * 32 + quad * 8];
        acc[f] = __builtin_amdgcn_mfma_f32_16x16x32_bf16(af[kc], bfr, acc[f], 0, 0, 0);
      }
    }

    // fused epilogue: logits for 64 cols, streaming row LSE
#pragma unroll
    for (int r = 0; r < 4; ++r) {
      float lg[4];
#pragma unroll
      for (int f = 0; f < 4; ++f) {
        const int cg = c0 + f * 16 + cL;
        const float sim = (cg == jw) ? sp[r] : acc[f][r];
        lg[f] = fmaf(wp, sim, bv);
      }
      float m = fmaxf(fmaxf(lg[0], lg[1]), fmaxf(lg[2], lg[3]));
#pragma unroll
      for (int off = 1; off < 16; off <<= 1) m = fmaxf(m, __shfl_xor(m, off, 64));
      float s = expf(lg[0] - m) + expf(lg[1] - m) + expf(lg[2] - m) + expf(lg[3] - m);
#pragma unroll
      for (int off = 1; off < 16; off <<= 1) s += __shfl_xor(s, off, 64);
      const float nm = fmaxf(rm[r], m);
      rs[r] = rs[r] * expf(rm[r] - nm) + s * expf(m - nm);
      rm[r] = nm;
    }
    __syncthreads();   // all waves done reading bs before next stage
  }

  if (cL == 0) {
#pragma unroll
    for (int r = 0; r < 4; ++r) {
      const int rg = r0 + wid * 16 + quad * 4 + r;
      pm[rg * 4 + cb] = rm[r];
      ps[rg * 4 + cb] = rs[r];
    }
  }
}

// ---------------- Kernel 3: combine col-split partials ----------------
__global__ __launch_bounds__(256) void k_combine(
    const float* __restrict__ pm, const float* __restrict__ ps,
    const float* __restrict__ simpos, const float* __restrict__ wptr,
    const float* __restrict__ bptr, float* __restrict__ p2) {
  __shared__ float red[4];
  const int tid = threadIdx.x;
  const int row = blockIdx.x * 256 + tid;
  const float wp = softplusf(wptr[0]);
  const float bv = bptr[0];
  float m0 = pm[row * 4 + 0], m1 = pm[row * 4 + 1];
  float m2 = pm[row * 4 + 2], m3 = pm[row * 4 + 3];
  float M = fmaxf(fmaxf(m0, m1), fmaxf(m2, m3));
  float S = ps[row * 4 + 0] * expf(m0 - M) + ps[row * 4 + 1] * expf(m1 - M)
          + ps[row * 4 + 2] * expf(m2 - M) + ps[row * 4 + 3] * expf(m3 - M);
  float dl = fmaf(wp, simpos[row], bv);
  float v = M + logf(S) - dl;
#pragma unroll
  for (int off = 32; off > 0; off >>= 1) v += __shfl_xor(v, off, 64);
  if ((tid & 63) == 0) red[tid >> 6] = v;
  __syncthreads();
  if (tid == 0) p2[blockIdx.x] = red[0] + red[1] + red[2] + red[3];
}

__global__ __launch_bounds__(64) void k_fin(const float* __restrict__ p2,
                                            float* __restrict__ out) {
  const int tid = threadIdx.x;
  float v = p2[tid];
#pragma unroll
  for (int off = 32; off > 0; off >>= 1) v += __shfl_xor(v, off, 64);
  if (tid == 0) out[0] = v * (1.0f / RR);
}

extern "C" void kernel_launch(void* const* d_in, const int* in_sizes, int n_in,
                              void* d_out, int out_size, void* d_ws, size_t ws_size,
                              hipStream_t stream) {
  const float* x = (const float*)d_in[0];
  const float* w = (const float*)d_in[1];
  const float* b = (const float*)d_in[2];
  float* out = (float*)d_out;
  float* ws = (float*)d_ws;

  unsigned short* mn = (unsigned short*)(ws + OFF_MN);
  float* nx     = ws + OFF_NX;
  float* simpos = ws + OFF_SIMPOS;
  float* pm     = ws + OFF_PM;
  float* ps     = ws + OFF_PS;
  float* p2     = ws + OFF_P2;

  k_pre<<<CC, 256, 0, stream>>>(x, mn, nx, simpos);
  k_gemm<<<1024, 256, 0, stream>>>(x, mn, nx, simpos, w, b, pm, ps);
  k_combine<<<RR / 256, 256, 0, stream>>>(pm, ps, simpos, w, b, p2);
  k_fin<<<1, 64, 0, stream>>>(p2, out);
}

// Round 3
// 114.579 us; speedup vs baseline: 7.6020x; 1.4440x over previous
//
#include <hip/hip_runtime.h>
#include <math.h>

#define CC 1024
#define SS 16
#define DD 512
#define RR (CC*SS)
#define EPSV 1e-8f
#define LDB 520   // 512 shorts + 8 pad -> 260 dwords (stride 4 mod 32, conflict-free b128)

typedef __attribute__((ext_vector_type(8))) short short8;
typedef __attribute__((ext_vector_type(4))) float f32x4;
typedef unsigned short ushort_t;

__device__ __forceinline__ unsigned short f2bf(float f) {
  unsigned u = __float_as_uint(f);
  u += 0x7fffu + ((u >> 16) & 1u);       // RNE
  return (unsigned short)(u >> 16);
}

__device__ __forceinline__ void async16(void* l, const void* g) {
  __builtin_amdgcn_global_load_lds(
      (const __attribute__((address_space(1))) void*)g,
      (__attribute__((address_space(3))) void*)l, 16, 0, 0);
}

__device__ __forceinline__ float softplusf(float v) {
  return (v > 20.f) ? v : log1pf(expf(v));
}

// ---------------- Kernel 1: per-class precompute ----------------
// Writes: mn (bf16 normalized mean rows), nx, simpos, and (if xn!=null)
// xn (bf16 row-normalized x).
__global__ __launch_bounds__(256) void k_pre(
    const float* __restrict__ x, ushort_t* __restrict__ mn,
    float* __restrict__ nx, float* __restrict__ simpos,
    ushort_t* __restrict__ xn) {
  __shared__ float xs[SS * DD];
  __shared__ float sums[DD];
  __shared__ float red[4];
  __shared__ float snm;
  __shared__ float rinv[SS];
  const int j = blockIdx.x, tid = threadIdx.x;
  const float4* xj = (const float4*)(x + (size_t)j * SS * DD);
  float4* xs4 = (float4*)xs;
  for (int i = tid; i < SS * DD / 4; i += 256) xs4[i] = xj[i];
  __syncthreads();
  float m2 = 0.f;
  for (int d = tid; d < DD; d += 256) {
    float s = 0.f;
#pragma unroll
    for (int i = 0; i < SS; ++i) s += xs[i * DD + d];
    sums[d] = s;
    float m = s * (1.0f / SS);
    m2 += m * m;
  }
#pragma unroll
  for (int off = 32; off > 0; off >>= 1) m2 += __shfl_xor(m2, off, 64);
  const int wid = tid >> 6, lane = tid & 63;
  if (lane == 0) red[wid] = m2;
  __syncthreads();
  if (tid == 0) snm = sqrtf(red[0] + red[1] + red[2] + red[3]);
  __syncthreads();
  const float inm = (1.0f / SS) / snm;
  for (int d = tid; d < DD; d += 256)
    mn[(size_t)j * DD + d] = f2bf(sums[d] * inm);
  for (int i = wid; i < SS; i += 4) {
    float nx2 = 0.f, dxs = 0.f, t2 = 0.f;
    for (int d = lane; d < DD; d += 64) {
      float xv = xs[i * DD + d];
      float sc = sums[d];
      nx2 = fmaf(xv, xv, nx2);
      dxs = fmaf(xv, sc, dxs);
      float tv = sc - xv;
      t2 = fmaf(tv, tv, t2);
    }
#pragma unroll
    for (int off = 32; off > 0; off >>= 1) {
      nx2 += __shfl_xor(nx2, off, 64);
      dxs += __shfl_xor(dxs, off, 64);
      t2  += __shfl_xor(t2,  off, 64);
    }
    if (lane == 0) {
      float nxv = sqrtf(nx2);
      float tn  = sqrtf(t2);
      float num = (dxs - nx2) * (1.0f / (SS - 1));
      float den = fmaxf(nxv * tn * (1.0f / (SS - 1)), EPSV);
      nx[j * SS + i] = nxv;
      rinv[i] = 1.0f / nxv;
      simpos[j * SS + i] = num / den;
    }
  }
  __syncthreads();
  if (xn) {
    unsigned* dst = (unsigned*)(xn + (size_t)j * SS * DD);
    for (int idx = tid; idx < SS * DD / 2; idx += 256) {
      const int e = idx * 2;
      const float ri = rinv[e >> 9];
      unsigned lo = f2bf(xs[e] * ri);
      unsigned hi = f2bf(xs[e + 1] * ri);
      dst[idx] = lo | (hi << 16);
    }
  }
}

// ---------------- Kernel 2: MFMA GEMM + fused exp-sum ----------------
// grid = 128 row-blocks x 2 col-splits = 256 blocks, 256 threads.
// Wave = 32 rows (2 row-tiles of 16), block = 128 rows, 512 cols in 8
// chunks of 64, B double-buffered via global_load_lds. No online max:
// logits bounded (|wp+|b|| small), per-lane running sum of exp.
template <bool USE_XN>
__global__ __launch_bounds__(256) void k_gemm(
    const float* __restrict__ x, const ushort_t* __restrict__ xn,
    const ushort_t* __restrict__ mn, const float* __restrict__ nx,
    const float* __restrict__ simpos, const float* __restrict__ wptr,
    const float* __restrict__ bptr, float* __restrict__ ps) {
  __shared__ ushort_t bs[2][64 * LDB];   // 133 KB
  const int tid = threadIdx.x;
  const int wid = tid >> 6, lane = tid & 63;
  const int cL = lane & 15, quad = lane >> 4;
  const int rb = (int)blockIdx.x >> 1, cb = (int)blockIdx.x & 1;
  const int r0 = rb * 128, cbase = cb * 512;
  const float wp = softplusf(wptr[0]), bv = bptr[0];

  short8 af[2][16];
  int jw[2];
  float sp[2][4], sacc[2][4];
#pragma unroll
  for (int rt = 0; rt < 2; ++rt) {
    const int row = r0 + wid * 32 + rt * 16 + cL;
    if (USE_XN) {
      const short8* src = (const short8*)(xn + (size_t)row * DD);
#pragma unroll
      for (int kc = 0; kc < 16; ++kc) af[rt][kc] = src[kc * 4 + quad];
    } else {
      const float* xr = x + (size_t)row * DD;
      const float invn = 1.0f / nx[row];
#pragma unroll
      for (int kc = 0; kc < 16; ++kc) {
        const int k0 = kc * 32 + quad * 8;
        float4 p = *(const float4*)(xr + k0);
        float4 q = *(const float4*)(xr + k0 + 4);
        short8 v;
        v[0] = f2bf(p.x * invn); v[1] = f2bf(p.y * invn);
        v[2] = f2bf(p.z * invn); v[3] = f2bf(p.w * invn);
        v[4] = f2bf(q.x * invn); v[5] = f2bf(q.y * invn);
        v[6] = f2bf(q.z * invn); v[7] = f2bf(q.w * invn);
        af[rt][kc] = v;
      }
    }
    jw[rt] = (r0 + wid * 32 + rt * 16) >> 4;
#pragma unroll
    for (int r = 0; r < 4; ++r) {
      sp[rt][r] = simpos[r0 + wid * 32 + rt * 16 + quad * 4 + r];
      sacc[rt][r] = 0.f;
    }
  }

  // stage chunk 0
  {
    const ushort_t* gsrc = mn + (size_t)cbase * DD;
#pragma unroll
    for (int t = 0; t < 16; ++t) {
      const int rr = wid + t * 4;
      async16(&bs[0][rr * LDB + lane * 8], gsrc + (size_t)rr * DD + lane * 8);
    }
  }
  __syncthreads();

  for (int cc = 0; cc < 8; ++cc) {
    if (cc < 7) {
      const ushort_t* gsrc = mn + (size_t)(cbase + (cc + 1) * 64) * DD;
      ushort_t* dst = bs[(cc + 1) & 1];
#pragma unroll
      for (int t = 0; t < 16; ++t) {
        const int rr = wid + t * 4;
        async16(&dst[rr * LDB + lane * 8], gsrc + (size_t)rr * DD + lane * 8);
      }
    }
    const ushort_t* B = bs[cc & 1];
    f32x4 acc[2][4];
#pragma unroll
    for (int rt = 0; rt < 2; ++rt)
#pragma unroll
      for (int f = 0; f < 4; ++f) acc[rt][f] = (f32x4){0.f, 0.f, 0.f, 0.f};
#pragma unroll
    for (int kc = 0; kc < 16; ++kc) {
      short8 bfr[4];
#pragma unroll
      for (int f = 0; f < 4; ++f)
        bfr[f] = *(const short8*)&B[(f * 16 + cL) * LDB + kc * 32 + quad * 8];
#pragma unroll
      for (int rt = 0; rt < 2; ++rt)
#pragma unroll
        for (int f = 0; f < 4; ++f)
          acc[rt][f] = __builtin_amdgcn_mfma_f32_16x16x32_bf16(
              af[rt][kc], bfr[f], acc[rt][f], 0, 0, 0);
    }
    const int c0 = cbase + cc * 64;
#pragma unroll
    for (int rt = 0; rt < 2; ++rt)
#pragma unroll
      for (int f = 0; f < 4; ++f) {
        const int cg = c0 + f * 16 + cL;
        const bool diag = (cg == jw[rt]);
#pragma unroll
        for (int r = 0; r < 4; ++r) {
          const float sim = diag ? sp[rt][r] : acc[rt][f][r];
          sacc[rt][r] += __expf(fmaf(wp, sim, bv));
        }
      }
    __syncthreads();
  }

#pragma unroll
  for (int rt = 0; rt < 2; ++rt)
#pragma unroll
    for (int r = 0; r < 4; ++r) {
      float v = sacc[rt][r];
#pragma unroll
      for (int off = 1; off < 16; off <<= 1) v += __shfl_xor(v, off, 64);
      if (cL == 0)
        ps[(size_t)(r0 + wid * 32 + rt * 16 + quad * 4 + r) * 2 + cb] = v;
    }
}

// ---------------- Kernel 3: per-row loss + block reduce ----------------
__global__ __launch_bounds__(256) void k_combine(
    const float* __restrict__ ps, const float* __restrict__ simpos,
    const float* __restrict__ wptr, const float* __restrict__ bptr,
    float* __restrict__ p2) {
  __shared__ float red[4];
  const int tid = threadIdx.x;
  const int row = blockIdx.x * 256 + tid;
  const float wp = softplusf(wptr[0]), bv = bptr[0];
  const float s = ps[row * 2] + ps[row * 2 + 1];
  float v = logf(s) - fmaf(wp, simpos[row], bv);
#pragma unroll
  for (int off = 32; off > 0; off >>= 1) v += __shfl_xor(v, off, 64);
  if ((tid & 63) == 0) red[tid >> 6] = v;
  __syncthreads();
  if (tid == 0) p2[blockIdx.x] = red[0] + red[1] + red[2] + red[3];
}

__global__ __launch_bounds__(64) void k_fin(const float* __restrict__ p2,
                                            float* __restrict__ out) {
  const int tid = threadIdx.x;
  float v = p2[tid];
#pragma unroll
  for (int off = 32; off > 0; off >>= 1) v += __shfl_xor(v, off, 64);
  if (tid == 0) out[0] = v * (1.0f / RR);
}

extern "C" void kernel_launch(void* const* d_in, const int* in_sizes, int n_in,
                              void* d_out, int out_size, void* d_ws, size_t ws_size,
                              hipStream_t stream) {
  const float* x = (const float*)d_in[0];
  const float* w = (const float*)d_in[1];
  const float* b = (const float*)d_in[2];
  float* out = (float*)d_out;

  const size_t xn_bytes = (size_t)RR * DD * 2;            // 16 MB
  const size_t rest = (size_t)CC * DD * 2 + (size_t)RR * 4 * 2 +
                      (size_t)RR * 2 * 4 + 64 * 4;
  const bool use_xn = ws_size >= xn_bytes + rest + 256;

  char* base = (char*)d_ws;
  ushort_t* xn = use_xn ? (ushort_t*)base : nullptr;
  char* p = base + (use_xn ? xn_bytes : 0);
  ushort_t* mn = (ushort_t*)p;  p += (size_t)CC * DD * 2;
  float* nx     = (float*)p;    p += (size_t)RR * 4;
  float* simpos = (float*)p;    p += (size_t)RR * 4;
  float* ps     = (float*)p;    p += (size_t)RR * 2 * 4;
  float* p2     = (float*)p;

  k_pre<<<CC, 256, 0, stream>>>(x, mn, nx, simpos, xn);
  if (use_xn)
    k_gemm<true><<<256, 256, 0, stream>>>(x, xn, mn, nx, simpos, w, b, ps);
  else
    k_gemm<false><<<256, 256, 0, stream>>>(x, xn, mn, nx, simpos, w, b, ps);
  k_combine<<<RR / 256, 256, 0, stream>>>(ps, simpos, w, b, p2);
  k_fin<<<1, 64, 0, stream>>>(p2, out);
}